// Round 7
// baseline (831.000 us; speedup 1.0000x reference)
//
#include <hip/hip_runtime.h>
#include <hip/hip_bf16.h>
#include <math.h>

#define NCH 32
#define BSH 6                   // nodes per bucket = 64
#define BNODES (1 << BSH)
#define MAXNB 2048              // LDS histogram capacity (N <= 131072)
#define PCH 1024                // payload LDS staging chunk (ints)

typedef unsigned short ushort_t;
typedef unsigned int uint_t;

static __device__ __forceinline__ float bf2f(ushort_t b) {
    return __uint_as_float(((uint_t)b) << 16);
}
static __device__ __forceinline__ ushort_t f2bf(float f) {
    __hip_bfloat16 h = __float2bfloat16(f);   // round-to-nearest-even
    return *reinterpret_cast<ushort_t*>(&h);
}
// Native LDS fp32 atomic (ds_add_f32). Plain atomicAdd on __shared__ float
// compiles to a CAS loop (safe-fp-atomics default) — R4-R6 post-mortem
// identified that as the invariant ~313us bottleneck.
static __device__ __forceinline__ void ldsAdd(float* p, float v) {
    unsafeAtomicAdd(p, v);
}

// ===========================================================================
// u = (W1-W2) x  (fp32, read LDS-locally per bucket)
// vh = W2 x      (bf16, the random-gather operand: 6.4 MB working set)
// y_e = u[src] + vh[tgt]
// k_gperm: gather vh ONCE per edge (bucket-ordered), fuse BN stats, emit
//          vperm (bucket-ordered bf16 copy) so apply is pure streaming.
// ===========================================================================

// --- per-node u (fp32) and vh (bf16) ---------------------------------------
__global__ __launch_bounds__(256) void k_uv(
    const float* __restrict__ x, const float* __restrict__ W,
    float* __restrict__ u, ushort_t* __restrict__ vh, int N)
{
    const int n = blockIdx.x * 256 + threadIdx.x;
    if (n >= N) return;
    float xs[NCH];
    const float4* __restrict__ ps = (const float4*)(x + (size_t)n * NCH);
#pragma unroll
    for (int i = 0; i < 8; ++i) {
        float4 a = ps[i];
        xs[4*i+0] = a.x; xs[4*i+1] = a.y; xs[4*i+2] = a.z; xs[4*i+3] = a.w;
    }
    float uu[NCH], vv[NCH];
#pragma unroll
    for (int c = 0; c < NCH; ++c) {
        const float* __restrict__ wr = W + c * 64;   // uniform -> s_load
        float su = 0.f, sv = 0.f;
#pragma unroll
        for (int k = 0; k < NCH; ++k) {
            su = fmaf(wr[k] - wr[32 + k], xs[k], su);
            sv = fmaf(wr[32 + k], xs[k], sv);
        }
        uu[c] = su; vv[c] = sv;
    }
    float4* __restrict__ pu = (float4*)(u + (size_t)n * NCH);
#pragma unroll
    for (int i = 0; i < 8; ++i)
        pu[i] = make_float4(uu[4*i], uu[4*i+1], uu[4*i+2], uu[4*i+3]);
    uint_t* __restrict__ pv = (uint_t*)(vh + (size_t)n * NCH);
#pragma unroll
    for (int i = 0; i < 16; ++i)
        pv[i] = (uint_t)f2bf(vv[2*i]) | ((uint_t)f2bf(vv[2*i+1]) << 16);
}

// --- bucket counts via LDS-privatized histogram ----------------------------
__global__ __launch_bounds__(256) void k_count(
    const int* __restrict__ srci, int* __restrict__ cnt_b, int E, int NB)
{
    __shared__ int h[MAXNB];
    for (int i = threadIdx.x; i < NB; i += 256) h[i] = 0;
    __syncthreads();
    const int stride = gridDim.x * 256;
    for (int e = blockIdx.x * 256 + threadIdx.x; e < E; e += stride)
        atomicAdd(&h[srci[e] >> BSH], 1);
    __syncthreads();
    for (int i = threadIdx.x; i < NB; i += 256)
        if (h[i]) atomicAdd(&cnt_b[i], h[i]);
}

// --- one-block exclusive scan over NB bucket counts ------------------------
__global__ __launch_bounds__(256) void k_scan_b(
    const int* __restrict__ cnt_b, int* __restrict__ off_b,
    int* __restrict__ cur_b, int NB)
{
    __shared__ int segsum[256];
    __shared__ int segoff[256];
    const int tid = threadIdx.x;
    const int per = (NB + 255) / 256;
    const int lo = tid * per;
    const int hi = min(lo + per, NB);
    int s = 0;
    for (int i = lo; i < hi; ++i) s += cnt_b[i];
    segsum[tid] = s;
    __syncthreads();
    if (tid == 0) {
        int a = 0;
        for (int i = 0; i < 256; ++i) { segoff[i] = a; a += segsum[i]; }
    }
    __syncthreads();
    int run = segoff[tid];
    for (int i = lo; i < hi; ++i) {
        off_b[i] = run;
        cur_b[i] = run;
        run += cnt_b[i];
    }
}

// --- scatter edges into buckets: payload = (src&63)<<17 | tgt --------------
__global__ __launch_bounds__(256) void k_bucket2(
    const int* __restrict__ srci, const int* __restrict__ tgti,
    int* __restrict__ cur_b, int* __restrict__ payload, int E)
{
    const int e = blockIdx.x * 256 + threadIdx.x;
    if (e >= E) return;
    const int s = srci[e];
    const int b = s >> BSH;
    const int pos = atomicAdd(&cur_b[b], 1);
    payload[pos] = ((s & (BNODES - 1)) << 17) | tgti[e];
}

// --- the ONE gather pass: vh[t] -> vperm (bucket-ordered) + BN stats -------
__global__ __launch_bounds__(256) void k_gperm(
    const float* __restrict__ u, const ushort_t* __restrict__ vh,
    const int* __restrict__ payload, const int* __restrict__ off_b,
    const int* __restrict__ cnt_b,
    ushort_t* __restrict__ vperm, float* __restrict__ partials, int N)
{
    __shared__ float uL[BNODES * NCH];
    __shared__ int pL[PCH];
    __shared__ float red[2][256];
    const int b = blockIdx.x;
    const int base = (b << BSH) * NCH;
    const int lim = N * NCH;
    for (int i = threadIdx.x; i < BNODES * NCH; i += 256) {
        const int gi = base + i;
        uL[i] = (gi < lim) ? u[gi] : 0.f;
    }

    const int off = off_b[b];
    const int cnt = cnt_b[b];
    const int g = threadIdx.x >> 5;     // edge sub-lane 0..7
    const int c = threadIdx.x & 31;     // channel
    float sum = 0.f, ssq = 0.f;

    for (int chunk = 0; chunk < cnt; chunk += PCH) {
        const int m = min(PCH, cnt - chunk);
        __syncthreads();
        for (int i = threadIdx.x; i < m; i += 256) pL[i] = payload[off + chunk + i];
        __syncthreads();
        int i = g;
        for (; i + 64 <= m; i += 64) {          // batch of 8 edges per group
            int w[8]; ushort_t vb[8];
#pragma unroll
            for (int k = 0; k < 8; ++k) w[k] = pL[i + 8*k];
#pragma unroll
            for (int k = 0; k < 8; ++k)
                vb[k] = vh[(size_t)(w[k] & 0x1FFFF) * NCH + c];   // 8 indep gathers
#pragma unroll
            for (int k = 0; k < 8; ++k) {
                const float y = uL[((w[k] >> 17) << 5) + c] + bf2f(vb[k]);
                sum += y;
                ssq = fmaf(y, y, ssq);
                vperm[(size_t)(off + chunk + i + 8*k) * NCH + c] = vb[k];
            }
        }
        for (; i < m; i += 8) {                 // tail
            const int w = pL[i];
            const ushort_t vb = vh[(size_t)(w & 0x1FFFF) * NCH + c];
            const float y = uL[((w >> 17) << 5) + c] + bf2f(vb);
            sum += y;
            ssq = fmaf(y, y, ssq);
            vperm[(size_t)(off + chunk + i) * NCH + c] = vb;
        }
    }

    red[0][threadIdx.x] = sum;
    red[1][threadIdx.x] = ssq;
    __syncthreads();
    if (threadIdx.x < 64) {
        const int which = threadIdx.x >> 5;   // 0: sum, 1: ssq
        const int cc = threadIdx.x & 31;
        float a = 0.f;
#pragma unroll
        for (int gg = 0; gg < 8; ++gg) a += red[which][(gg << 5) + cc];
        partials[(size_t)b * 64 + (which << 5) + cc] = a;
    }
}

// --- combine partials -> BN affine a,b -------------------------------------
__global__ __launch_bounds__(256) void k_finalize(
    const float* __restrict__ partials, int nblocks,
    const float* __restrict__ gamma, const float* __restrict__ beta,
    float* __restrict__ ab, float invE)
{
    __shared__ float acc[4][64];
    const int vtx = threadIdx.x & 63, chunk = threadIdx.x >> 6;
    float s = 0.f;
    for (int r = chunk; r < nblocks; r += 4) s += partials[(size_t)r * 64 + vtx];
    acc[chunk][vtx] = s;
    __syncthreads();
    if (threadIdx.x < 64) acc[0][vtx] = acc[0][vtx] + acc[1][vtx] + acc[2][vtx] + acc[3][vtx];
    __syncthreads();
    if (threadIdx.x < 32) {
        const int c = threadIdx.x;
        float mean = acc[0][c] * invE;
        float var  = acc[0][32 + c] * invE - mean * mean;
        float rstd = rsqrtf(var + 1e-5f);
        float a = gamma[c] * rstd;
        ab[c] = a; ab[32 + c] = beta[c] - mean * a;
    }
}

// --- apply: STREAMING vperm read, native ds_add_f32 accumulate -------------
__global__ __launch_bounds__(256) void k_apply_v2(
    const float* __restrict__ u, const ushort_t* __restrict__ vperm,
    const int* __restrict__ payload, const int* __restrict__ off_b,
    const int* __restrict__ cnt_b, const float* __restrict__ ab,
    float* __restrict__ out, int N)
{
    __shared__ float uL[BNODES * NCH];
    __shared__ float accL[BNODES * NCH];
    __shared__ int pL[PCH];
    const int b = blockIdx.x;
    const int base = (b << BSH) * NCH;
    const int lim = N * NCH;
    for (int i = threadIdx.x; i < BNODES * NCH; i += 256) {
        const int gi = base + i;
        uL[i] = (gi < lim) ? u[gi] : 0.f;
        accL[i] = 0.f;
    }

    const int off = off_b[b];
    const int cnt = cnt_b[b];
    const int g = threadIdx.x >> 5;
    const int c = threadIdx.x & 31;
    const float a_c = ab[c];
    const float b_c = ab[32 + c];

    for (int chunk = 0; chunk < cnt; chunk += PCH) {
        const int m = min(PCH, cnt - chunk);
        __syncthreads();
        for (int i = threadIdx.x; i < m; i += 256) pL[i] = payload[off + chunk + i];
        __syncthreads();
        int i = g;
        for (; i + 64 <= m; i += 64) {
            int w[8]; ushort_t vb[8];
#pragma unroll
            for (int k = 0; k < 8; ++k) w[k] = pL[i + 8*k];
#pragma unroll
            for (int k = 0; k < 8; ++k)
                vb[k] = vperm[(size_t)(off + chunk + i + 8*k) * NCH + c];  // streaming
#pragma unroll
            for (int k = 0; k < 8; ++k) {
                const int sl = w[k] >> 17;
                const float y = uL[(sl << 5) + c] + bf2f(vb[k]);
                float z = fmaf(a_c, y, b_c);
                z = (z > 0.f) ? z : (__expf(z) - 1.0f);
                ldsAdd(&accL[(sl << 5) + c], z);   // native ds_add_f32
            }
        }
        for (; i < m; i += 8) {
            const int w = pL[i];
            const int sl = w >> 17;
            const float y = uL[(sl << 5) + c]
                          + bf2f(vperm[(size_t)(off + chunk + i) * NCH + c]);
            float z = fmaf(a_c, y, b_c);
            z = (z > 0.f) ? z : (__expf(z) - 1.0f);
            ldsAdd(&accL[(sl << 5) + c], z);
        }
    }
    __syncthreads();
    for (int i = threadIdx.x; i < BNODES * NCH; i += 256) {
        const int gi = base + i;
        if (gi < lim) out[gi] = accL[i];
    }
}

// ===========================================================================
// FALLBACK (two bf16 random-gather passes) — if ws can't hold vperm
// ===========================================================================
__global__ __launch_bounds__(256) void k_stats_fb(
    const float* __restrict__ u, const ushort_t* __restrict__ vh,
    const int* __restrict__ payload, const int* __restrict__ off_b,
    const int* __restrict__ cnt_b,
    float* __restrict__ partials, int N)
{
    __shared__ float uL[BNODES * NCH];
    __shared__ int pL[PCH];
    __shared__ float red[2][256];
    const int b = blockIdx.x;
    const int base = (b << BSH) * NCH;
    const int lim = N * NCH;
    for (int i = threadIdx.x; i < BNODES * NCH; i += 256) {
        const int gi = base + i;
        uL[i] = (gi < lim) ? u[gi] : 0.f;
    }
    const int off = off_b[b];
    const int cnt = cnt_b[b];
    const int g = threadIdx.x >> 5;
    const int c = threadIdx.x & 31;
    float sum = 0.f, ssq = 0.f;
    for (int chunk = 0; chunk < cnt; chunk += PCH) {
        const int m = min(PCH, cnt - chunk);
        __syncthreads();
        for (int i = threadIdx.x; i < m; i += 256) pL[i] = payload[off + chunk + i];
        __syncthreads();
        for (int i = g; i < m; i += 8) {
            const int w = pL[i];
            const float y = uL[((w >> 17) << 5) + c]
                          + bf2f(vh[(size_t)(w & 0x1FFFF) * NCH + c]);
            sum += y;
            ssq = fmaf(y, y, ssq);
        }
    }
    red[0][threadIdx.x] = sum;
    red[1][threadIdx.x] = ssq;
    __syncthreads();
    if (threadIdx.x < 64) {
        const int which = threadIdx.x >> 5;
        const int cc = threadIdx.x & 31;
        float a = 0.f;
#pragma unroll
        for (int gg = 0; gg < 8; ++gg) a += red[which][(gg << 5) + cc];
        partials[(size_t)b * 64 + (which << 5) + cc] = a;
    }
}

__global__ __launch_bounds__(256) void k_apply_fb(
    const float* __restrict__ u, const ushort_t* __restrict__ vh,
    const int* __restrict__ payload, const int* __restrict__ off_b,
    const int* __restrict__ cnt_b, const float* __restrict__ ab,
    float* __restrict__ out, int N)
{
    __shared__ float uL[BNODES * NCH];
    __shared__ float accL[BNODES * NCH];
    __shared__ int pL[PCH];
    const int b = blockIdx.x;
    const int base = (b << BSH) * NCH;
    const int lim = N * NCH;
    for (int i = threadIdx.x; i < BNODES * NCH; i += 256) {
        const int gi = base + i;
        uL[i] = (gi < lim) ? u[gi] : 0.f;
        accL[i] = 0.f;
    }
    const int off = off_b[b];
    const int cnt = cnt_b[b];
    const int g = threadIdx.x >> 5;
    const int c = threadIdx.x & 31;
    const float a_c = ab[c];
    const float b_c = ab[32 + c];
    for (int chunk = 0; chunk < cnt; chunk += PCH) {
        const int m = min(PCH, cnt - chunk);
        __syncthreads();
        for (int i = threadIdx.x; i < m; i += 256) pL[i] = payload[off + chunk + i];
        __syncthreads();
        for (int i = g; i < m; i += 8) {
            const int w = pL[i];
            const int sl = w >> 17;
            const float y = uL[(sl << 5) + c]
                          + bf2f(vh[(size_t)(w & 0x1FFFF) * NCH + c]);
            float z = fmaf(a_c, y, b_c);
            z = (z > 0.f) ? z : (__expf(z) - 1.0f);
            ldsAdd(&accL[(sl << 5) + c], z);
        }
    }
    __syncthreads();
    for (int i = threadIdx.x; i < BNODES * NCH; i += 256) {
        const int gi = base + i;
        if (gi < lim) out[gi] = accL[i];
    }
}

// ===========================================================================
extern "C" void kernel_launch(void* const* d_in, const int* in_sizes, int n_in,
                              void* d_out, int out_size, void* d_ws, size_t ws_size,
                              hipStream_t stream)
{
    const float* x     = (const float*)d_in[0];
    const int*   ei    = (const int*)d_in[1];
    const float* W     = (const float*)d_in[2];
    const float* gamma = (const float*)d_in[3];
    const float* beta  = (const float*)d_in[4];
    const int E = in_sizes[1] / 2;
    const int N = in_sizes[0] / NCH;
    const int* srci = ei;
    const int* tgti = ei + E;

    const int NB = (N + BNODES - 1) >> BSH;

    // common ws prefix: u[N*32]f32 | vh[N*32]bf16 | payload[E] | cnt/off/cur[NB*3]
    //                   | partials[NB*64]f32 | ab[64]f32 | (fast only) vperm[E*32]bf16
    size_t base_need = (size_t)N * NCH * 4 + (size_t)N * NCH * 2
                     + ((size_t)E + 3 * NB) * 4
                     + ((size_t)NB * 64 + 64) * 4;
    size_t vperm_bytes = (size_t)E * NCH * 2;

    float*    u       = (float*)d_ws;
    ushort_t* vh      = (ushort_t*)(u + (size_t)N * NCH);
    int*      payload = (int*)(vh + (size_t)N * NCH);
    int*      cnt_b   = payload + E;
    int*      off_b   = cnt_b + NB;
    int*      cur_b   = off_b + NB;
    float*    partials= (float*)(cur_b + NB);
    float*    ab      = partials + (size_t)NB * 64;
    ushort_t* vperm   = (ushort_t*)(ab + 64);

    hipMemsetAsync(cnt_b, 0, (size_t)NB * sizeof(int), stream);
    k_uv<<<(N + 255) / 256, 256, 0, stream>>>(x, W, u, vh, N);
    k_count<<<128, 256, 0, stream>>>(srci, cnt_b, E, NB);
    k_scan_b<<<1, 256, 0, stream>>>(cnt_b, off_b, cur_b, NB);
    k_bucket2<<<(E + 255) / 256, 256, 0, stream>>>(srci, tgti, cur_b, payload, E);

    if (N <= 131072 && NB <= MAXNB && ws_size >= base_need + vperm_bytes) {
        // FAST: single gather pass (fused stats) + streaming apply
        k_gperm<<<NB, 256, 0, stream>>>(u, vh, payload, off_b, cnt_b, vperm, partials, N);
        k_finalize<<<1, 256, 0, stream>>>(partials, NB, gamma, beta, ab, 1.0f / (float)E);
        k_apply_v2<<<NB, 256, 0, stream>>>(u, vperm, payload, off_b, cnt_b, ab,
                                           (float*)d_out, N);
    } else {
        // FALLBACK: two bf16-gather passes
        k_stats_fb<<<NB, 256, 0, stream>>>(u, vh, payload, off_b, cnt_b, partials, N);
        k_finalize<<<1, 256, 0, stream>>>(partials, NB, gamma, beta, ab, 1.0f / (float)E);
        k_apply_fb<<<NB, 256, 0, stream>>>(u, vh, payload, off_b, cnt_b, ab,
                                           (float*)d_out, N);
    }
}

// Round 8
// 605.298 us; speedup vs baseline: 1.3729x; 1.3729x over previous
//
#include <hip/hip_runtime.h>
#include <hip/hip_bf16.h>
#include <math.h>

#define NCH 32

typedef unsigned short ushort_t;
typedef unsigned int uint_t;

static __device__ __forceinline__ float bf2f(ushort_t b) {
    return __uint_as_float(((uint_t)b) << 16);
}
static __device__ __forceinline__ ushort_t f2bf(float f) {
    __hip_bfloat16 h = __float2bfloat16(f);   // round-to-nearest-even
    return *reinterpret_cast<ushort_t*>(&h);
}

// ===========================================================================
// FLAT pipeline (round-8): no per-bucket serial chains.
//   u = (W1-W2) x (fp32), vh = W2 x (bf16);  y_e = u[src] + vh[tgt]
//   1) k_stats_flat: thread-per-edge gathers, reg sum/ssq, fused cnt_n[src]++
//   2) k_scan_n:     exclusive scan of per-node degrees
//   3) k_tperm:      flat counting-sort scatter of tgt ids by src node
//   4) k_apply_node: one 32-lane group per node, register accumulate, store
// ===========================================================================

// --- per-node u (fp32) and vh (bf16) ---------------------------------------
__global__ __launch_bounds__(256) void k_uv(
    const float* __restrict__ x, const float* __restrict__ W,
    float* __restrict__ u, ushort_t* __restrict__ vh, int N)
{
    const int n = blockIdx.x * 256 + threadIdx.x;
    if (n >= N) return;
    float xs[NCH];
    const float4* __restrict__ ps = (const float4*)(x + (size_t)n * NCH);
#pragma unroll
    for (int i = 0; i < 8; ++i) {
        float4 a = ps[i];
        xs[4*i+0] = a.x; xs[4*i+1] = a.y; xs[4*i+2] = a.z; xs[4*i+3] = a.w;
    }
    float uu[NCH], vv[NCH];
#pragma unroll
    for (int c = 0; c < NCH; ++c) {
        const float* __restrict__ wr = W + c * 64;   // uniform -> s_load
        float su = 0.f, sv = 0.f;
#pragma unroll
        for (int k = 0; k < NCH; ++k) {
            su = fmaf(wr[k] - wr[32 + k], xs[k], su);
            sv = fmaf(wr[32 + k], xs[k], sv);
        }
        uu[c] = su; vv[c] = sv;
    }
    float4* __restrict__ pu = (float4*)(u + (size_t)n * NCH);
#pragma unroll
    for (int i = 0; i < 8; ++i)
        pu[i] = make_float4(uu[4*i], uu[4*i+1], uu[4*i+2], uu[4*i+3]);
    uint_t* __restrict__ pv = (uint_t*)(vh + (size_t)n * NCH);
#pragma unroll
    for (int i = 0; i < 16; ++i)
        pv[i] = (uint_t)f2bf(vv[2*i]) | ((uint_t)f2bf(vv[2*i+1]) << 16);
}

// --- flat stats: per-edge y = u[s] + vh[t]; reg sum/ssq; fused histogram ---
__global__ __launch_bounds__(256) void k_stats_flat(
    const float* __restrict__ u, const ushort_t* __restrict__ vh,
    const int* __restrict__ srci, const int* __restrict__ tgti,
    int* __restrict__ cnt_n,
    float* __restrict__ partials, int E)
{
    float sum[NCH], ssq[NCH];
#pragma unroll
    for (int c = 0; c < NCH; ++c) { sum[c] = 0.f; ssq[c] = 0.f; }

    const int stride = gridDim.x * 256;
    for (int e = blockIdx.x * 256 + threadIdx.x; e < E; e += stride) {
        const int s = srci[e];
        const int t = tgti[e];
        atomicAdd(&cnt_n[s], 1);          // native int RMW, fire-and-forget
        const float4* __restrict__ pu = (const float4*)(u + (size_t)s * NCH);
        const uint4*  __restrict__ pv = (const uint4*)(vh + (size_t)t * NCH);
        float us[NCH];
        uint_t vb[NCH];
#pragma unroll
        for (int i = 0; i < 8; ++i) {
            float4 a = pu[i];
            us[4*i+0] = a.x; us[4*i+1] = a.y; us[4*i+2] = a.z; us[4*i+3] = a.w;
        }
#pragma unroll
        for (int i = 0; i < 2; ++i) {
            uint4 q = pv[i];
            uint_t ww[4] = {q.x, q.y, q.z, q.w};
#pragma unroll
            for (int j = 0; j < 4; ++j) {
                vb[16*i + 4*j + 0] = (ushort_t)(ww[j] & 0xFFFF);
                vb[16*i + 4*j + 1] = 0;  // placeholder, fixed below
            }
#pragma unroll
            for (int j = 0; j < 4; ++j) {
                const int base = 16*i + 4*j;
                uint_t w2 = ww[j];
                // each uint holds 2 bf16 (lo, hi) -> channels base.., but we
                // packed 2 per uint in k_uv: uint i covers channels 2i,2i+1.
                (void)w2; (void)base;
            }
        }
        // unpack properly: uint q.{x,y,z,w} of pv[i] are uints 4i..4i+3,
        // uint k covers channels 2k, 2k+1
        {
            const uint_t* __restrict__ pw = (const uint_t*)(vh + (size_t)t * NCH);
#pragma unroll
            for (int k = 0; k < 16; ++k) {
                // (loads already issued above via uint4; compiler folds)
                uint_t w2 = pw[k];
                float v0 = __uint_as_float((w2 & 0xFFFFu) << 16);
                float v1 = __uint_as_float(w2 & 0xFFFF0000u);
                const int c0 = 2*k, c1 = 2*k + 1;
                float y0 = us[c0] + v0;
                float y1 = us[c1] + v1;
                sum[c0] += y0; ssq[c0] = fmaf(y0, y0, ssq[c0]);
                sum[c1] += y1; ssq[c1] = fmaf(y1, y1, ssq[c1]);
            }
        }
    }

#pragma unroll
    for (int c = 0; c < NCH; ++c) {
#pragma unroll
        for (int off = 32; off > 0; off >>= 1) {
            sum[c] += __shfl_down(sum[c], off);
            ssq[c] += __shfl_down(ssq[c], off);
        }
    }
    __shared__ float red[4][64];
    const int lane = threadIdx.x & 63, wave = threadIdx.x >> 6;
    if (lane == 0) {
#pragma unroll
        for (int c = 0; c < NCH; ++c) { red[wave][c] = sum[c]; red[wave][NCH+c] = ssq[c]; }
    }
    __syncthreads();
    if (threadIdx.x < 64)
        partials[(size_t)blockIdx.x * 64 + threadIdx.x] =
            red[0][threadIdx.x] + red[1][threadIdx.x]
          + red[2][threadIdx.x] + red[3][threadIdx.x];
}

// --- exclusive scan over N node degrees (single 1024-thread block) ---------
__global__ __launch_bounds__(1024) void k_scan_n(
    const int* __restrict__ counts,
    int* __restrict__ offsets,
    int* __restrict__ cursor,
    int N)
{
    const int tid = threadIdx.x;
    const int per = (N + 1023) / 1024;
    const int lo = tid * per;
    const int hi = min(lo + per, N);
    int s = 0;
    for (int i = lo; i < hi; ++i) s += counts[i];

    const int lane = tid & 63, wv = tid >> 6;
    int val = s;
#pragma unroll
    for (int off = 1; off < 64; off <<= 1) {
        int t = __shfl_up(val, off);
        if (lane >= off) val += t;
    }
    __shared__ int wsum[16];
    __shared__ int woff[16];
    if (lane == 63) wsum[wv] = val;
    __syncthreads();
    if (tid == 0) {
        int a = 0;
#pragma unroll
        for (int w = 0; w < 16; ++w) { woff[w] = a; a += wsum[w]; }
    }
    __syncthreads();
    int run = woff[wv] + (val - s);
    for (int i = lo; i < hi; ++i) {
        offsets[i] = run;
        cursor[i]  = run;
        run += counts[i];
    }
}

// --- flat counting-sort scatter: tperm[pos] = tgt, pos per-src cursor ------
__global__ __launch_bounds__(256) void k_tperm(
    const int* __restrict__ srci, const int* __restrict__ tgti,
    int* __restrict__ cur_n, int* __restrict__ tperm, int E)
{
    const int e = blockIdx.x * 256 + threadIdx.x;
    if (e >= E) return;
    const int s = srci[e];
    const int pos = atomicAdd(&cur_n[s], 1);
    tperm[pos] = tgti[e];
}

// --- combine partials -> BN affine a,b -------------------------------------
__global__ __launch_bounds__(256) void k_finalize(
    const float* __restrict__ partials, int nblocks,
    const float* __restrict__ gamma, const float* __restrict__ beta,
    float* __restrict__ ab, float invE)
{
    __shared__ float acc[4][64];
    const int vtx = threadIdx.x & 63, chunk = threadIdx.x >> 6;
    float s = 0.f;
    for (int r = chunk; r < nblocks; r += 4) s += partials[(size_t)r * 64 + vtx];
    acc[chunk][vtx] = s;
    __syncthreads();
    if (threadIdx.x < 64) acc[0][vtx] = acc[0][vtx] + acc[1][vtx] + acc[2][vtx] + acc[3][vtx];
    __syncthreads();
    if (threadIdx.x < 32) {
        const int c = threadIdx.x;
        float mean = acc[0][c] * invE;
        float var  = acc[0][32 + c] * invE - mean * mean;
        float rstd = rsqrtf(var + 1e-5f);
        float a = gamma[c] * rstd;
        ab[c] = a; ab[32 + c] = beta[c] - mean * a;
    }
}

// --- per-node apply: 32-lane group per node, register accumulate -----------
__global__ __launch_bounds__(256) void k_apply_node(
    const float* __restrict__ u, const ushort_t* __restrict__ vh,
    const int* __restrict__ tperm, const int* __restrict__ off_n,
    const int* __restrict__ cnt_n, const float* __restrict__ ab,
    float* __restrict__ out, int N)
{
    const int n = blockIdx.x * 8 + (threadIdx.x >> 5);
    const int c = threadIdx.x & 31;
    if (n >= N) return;

    const int off = off_n[n];
    const int deg = cnt_n[n];
    const float un  = u[(size_t)n * NCH + c];
    const float a_c = ab[c];
    const float b_c = ab[32 + c];

    float acc = 0.f;
    int i = 0;
    for (; i + 4 <= deg; i += 4) {
        int t0 = tperm[off + i + 0];
        int t1 = tperm[off + i + 1];
        int t2 = tperm[off + i + 2];
        int t3 = tperm[off + i + 3];
        ushort_t v0 = vh[(size_t)t0 * NCH + c];
        ushort_t v1 = vh[(size_t)t1 * NCH + c];
        ushort_t v2 = vh[(size_t)t2 * NCH + c];
        ushort_t v3 = vh[(size_t)t3 * NCH + c];
        float z0 = fmaf(a_c, un + bf2f(v0), b_c);
        float z1 = fmaf(a_c, un + bf2f(v1), b_c);
        float z2 = fmaf(a_c, un + bf2f(v2), b_c);
        float z3 = fmaf(a_c, un + bf2f(v3), b_c);
        z0 = (z0 > 0.f) ? z0 : (__expf(z0) - 1.0f);
        z1 = (z1 > 0.f) ? z1 : (__expf(z1) - 1.0f);
        z2 = (z2 > 0.f) ? z2 : (__expf(z2) - 1.0f);
        z3 = (z3 > 0.f) ? z3 : (__expf(z3) - 1.0f);
        acc += (z0 + z1) + (z2 + z3);
    }
    for (; i < deg; ++i) {
        int t = tperm[off + i];
        float z = fmaf(a_c, un + bf2f(vh[(size_t)t * NCH + c]), b_c);
        z = (z > 0.f) ? z : (__expf(z) - 1.0f);
        acc += z;
    }
    out[(size_t)n * NCH + c] = acc;
}

// ===========================================================================
// FALLBACK (round-1 proven path) — only if ws too small
// ===========================================================================
__global__ __launch_bounds__(256) void k_stats_hist(
    const float* __restrict__ x,
    const int* __restrict__ srci, const int* __restrict__ tgti,
    const float* __restrict__ W,
    float* __restrict__ partials, int E)
{
    float sum[NCH], ssq[NCH];
#pragma unroll
    for (int c = 0; c < NCH; ++c) { sum[c] = 0.f; ssq[c] = 0.f; }
    const int stride = gridDim.x * blockDim.x;
    for (int e = blockIdx.x * blockDim.x + threadIdx.x; e < E; e += stride) {
        const int s = srci[e], t = tgti[e];
        const float4* ps = (const float4*)(x + (size_t)s * NCH);
        const float4* pt = (const float4*)(x + (size_t)t * NCH);
        float xs[NCH], dx[NCH];
#pragma unroll
        for (int i = 0; i < 8; ++i) {
            float4 a = ps[i], bb = pt[i];
            xs[4*i+0] = a.x; xs[4*i+1] = a.y; xs[4*i+2] = a.z; xs[4*i+3] = a.w;
            dx[4*i+0] = bb.x - a.x; dx[4*i+1] = bb.y - a.y;
            dx[4*i+2] = bb.z - a.z; dx[4*i+3] = bb.w - a.w;
        }
#pragma unroll
        for (int c = 0; c < NCH; ++c) {
            const float* wr = W + c * 64;
            float y = 0.f;
#pragma unroll
            for (int k = 0; k < NCH; ++k) y = fmaf(wr[k], xs[k], y);
#pragma unroll
            for (int k = 0; k < NCH; ++k) y = fmaf(wr[32 + k], dx[k], y);
            sum[c] += y;
            ssq[c] = fmaf(y, y, ssq[c]);
        }
    }
#pragma unroll
    for (int c = 0; c < NCH; ++c) {
#pragma unroll
        for (int off = 32; off > 0; off >>= 1) {
            sum[c] += __shfl_down(sum[c], off);
            ssq[c] += __shfl_down(ssq[c], off);
        }
    }
    __shared__ float red[4][64];
    const int lane = threadIdx.x & 63, wave = threadIdx.x >> 6;
    if (lane == 0) {
#pragma unroll
        for (int c = 0; c < NCH; ++c) { red[wave][c] = sum[c]; red[wave][NCH+c] = ssq[c]; }
    }
    __syncthreads();
    if (threadIdx.x < 64)
        partials[(size_t)blockIdx.x * 64 + threadIdx.x] =
            red[0][threadIdx.x] + red[1][threadIdx.x] + red[2][threadIdx.x] + red[3][threadIdx.x];
}

__global__ __launch_bounds__(256) void k_apply_atomic(
    const float* __restrict__ x,
    const int* __restrict__ srci, const int* __restrict__ tgti,
    const float* __restrict__ W, const float* __restrict__ ab,
    float* __restrict__ out, int E)
{
    const int e = blockIdx.x * 256 + threadIdx.x;
    if (e >= E) return;
    const int s = srci[e], t = tgti[e];
    const float4* ps = (const float4*)(x + (size_t)s * NCH);
    const float4* pt = (const float4*)(x + (size_t)t * NCH);
    float xs[NCH], dx[NCH];
#pragma unroll
    for (int i = 0; i < 8; ++i) {
        float4 a = ps[i], bb = pt[i];
        xs[4*i+0] = a.x; xs[4*i+1] = a.y; xs[4*i+2] = a.z; xs[4*i+3] = a.w;
        dx[4*i+0] = bb.x - a.x; dx[4*i+1] = bb.y - a.y;
        dx[4*i+2] = bb.z - a.z; dx[4*i+3] = bb.w - a.w;
    }
    float* orow = out + (size_t)s * NCH;
#pragma unroll
    for (int c = 0; c < NCH; ++c) {
        const float* wr = W + c * 64;
        float y = 0.f;
#pragma unroll
        for (int k = 0; k < NCH; ++k) y = fmaf(wr[k], xs[k], y);
#pragma unroll
        for (int k = 0; k < NCH; ++k) y = fmaf(wr[32 + k], dx[k], y);
        float z = fmaf(ab[c], y, ab[32 + c]);
        z = (z > 0.f) ? z : (__expf(z) - 1.0f);
        atomicAdd(orow + c, z);
    }
}

// ===========================================================================
extern "C" void kernel_launch(void* const* d_in, const int* in_sizes, int n_in,
                              void* d_out, int out_size, void* d_ws, size_t ws_size,
                              hipStream_t stream)
{
    const float* x     = (const float*)d_in[0];
    const int*   ei    = (const int*)d_in[1];
    const float* W     = (const float*)d_in[2];
    const float* gamma = (const float*)d_in[3];
    const float* beta  = (const float*)d_in[4];
    const int E = in_sizes[1] / 2;
    const int N = in_sizes[0] / NCH;
    const int* srci = ei;
    const int* tgti = ei + E;

    const int SB = 512;   // stats grid

    // ws: u[N*32]f32 | vh[N*32]bf16 | tperm[E] | cnt_n[N] off_n[N] cur_n[N]
    //     | partials[SB*64]f32 | ab[64]f32
    size_t need = (size_t)N * NCH * 4 + (size_t)N * NCH * 2
                + ((size_t)E + 3 * (size_t)N) * 4
                + ((size_t)SB * 64 + 64) * 4;

    if (ws_size >= need) {
        float*    u       = (float*)d_ws;
        ushort_t* vh      = (ushort_t*)(u + (size_t)N * NCH);
        int*      tperm   = (int*)(vh + (size_t)N * NCH);
        int*      cnt_n   = tperm + E;
        int*      off_n   = cnt_n + N;
        int*      cur_n   = off_n + N;
        float*    partials= (float*)(cur_n + N);
        float*    ab      = partials + (size_t)SB * 64;

        hipMemsetAsync(cnt_n, 0, (size_t)N * sizeof(int), stream);
        k_uv<<<(N + 255) / 256, 256, 0, stream>>>(x, W, u, vh, N);
        k_stats_flat<<<SB, 256, 0, stream>>>(u, vh, srci, tgti, cnt_n, partials, E);
        k_scan_n<<<1, 1024, 0, stream>>>(cnt_n, off_n, cur_n, N);
        k_tperm<<<(E + 255) / 256, 256, 0, stream>>>(srci, tgti, cur_n, tperm, E);
        k_finalize<<<1, 256, 0, stream>>>(partials, SB, gamma, beta, ab, 1.0f / (float)E);
        k_apply_node<<<(N + 7) / 8, 256, 0, stream>>>(u, vh, tperm, off_n, cnt_n, ab,
                                                      (float*)d_out, N);
    } else {
        const int SBf = 512;
        float* ab       = (float*)d_ws;
        float* partials = ab + 64;
        hipMemsetAsync(d_out, 0, (size_t)out_size * sizeof(float), stream);
        k_stats_hist<<<SBf, 256, 0, stream>>>(x, srci, tgti, W, partials, E);
        k_finalize<<<1, 256, 0, stream>>>(partials, SBf, gamma, beta, ab, 1.0f / (float)E);
        k_apply_atomic<<<(E + 255) / 256, 256, 0, stream>>>(x, srci, tgti, W, ab,
                                                            (float*)d_out, E);
    }
}

// Round 9
// 433.019 us; speedup vs baseline: 1.9191x; 1.3979x over previous
//
#include <hip/hip_runtime.h>
#include <hip/hip_bf16.h>
#include <math.h>

#define NCH 32

typedef unsigned short ushort_t;
typedef unsigned int uint_t;

static __device__ __forceinline__ float bf2f(ushort_t b) {
    return __uint_as_float(((uint_t)b) << 16);
}
static __device__ __forceinline__ ushort_t f2bf(float f) {
    __hip_bfloat16 h = __float2bfloat16(f);   // round-to-nearest-even
    return *reinterpret_cast<ushort_t*>(&h);
}

// ===========================================================================
// FLAT pipeline (round-9): round-8 + parallel 3-kernel scan
//   (round-8 post-mortem: single-block k_scan_n was 231us = 38% of total)
// ===========================================================================

// --- per-node u (fp32) and vh (bf16) ---------------------------------------
__global__ __launch_bounds__(256) void k_uv(
    const float* __restrict__ x, const float* __restrict__ W,
    float* __restrict__ u, ushort_t* __restrict__ vh, int N)
{
    const int n = blockIdx.x * 256 + threadIdx.x;
    if (n >= N) return;
    float xs[NCH];
    const float4* __restrict__ ps = (const float4*)(x + (size_t)n * NCH);
#pragma unroll
    for (int i = 0; i < 8; ++i) {
        float4 a = ps[i];
        xs[4*i+0] = a.x; xs[4*i+1] = a.y; xs[4*i+2] = a.z; xs[4*i+3] = a.w;
    }
    float uu[NCH], vv[NCH];
#pragma unroll
    for (int c = 0; c < NCH; ++c) {
        const float* __restrict__ wr = W + c * 64;   // uniform -> s_load
        float su = 0.f, sv = 0.f;
#pragma unroll
        for (int k = 0; k < NCH; ++k) {
            su = fmaf(wr[k] - wr[32 + k], xs[k], su);
            sv = fmaf(wr[32 + k], xs[k], sv);
        }
        uu[c] = su; vv[c] = sv;
    }
    float4* __restrict__ pu = (float4*)(u + (size_t)n * NCH);
#pragma unroll
    for (int i = 0; i < 8; ++i)
        pu[i] = make_float4(uu[4*i], uu[4*i+1], uu[4*i+2], uu[4*i+3]);
    uint_t* __restrict__ pv = (uint_t*)(vh + (size_t)n * NCH);
#pragma unroll
    for (int i = 0; i < 16; ++i)
        pv[i] = (uint_t)f2bf(vv[2*i]) | ((uint_t)f2bf(vv[2*i+1]) << 16);
}

// --- flat stats: per-edge y = u[s] + vh[t]; reg sum/ssq; fused histogram ---
__global__ __launch_bounds__(256) void k_stats_flat(
    const float* __restrict__ u, const ushort_t* __restrict__ vh,
    const int* __restrict__ srci, const int* __restrict__ tgti,
    int* __restrict__ cnt_n,
    float* __restrict__ partials, int E)
{
    float sum[NCH], ssq[NCH];
#pragma unroll
    for (int c = 0; c < NCH; ++c) { sum[c] = 0.f; ssq[c] = 0.f; }

    const int stride = gridDim.x * 256;
    for (int e = blockIdx.x * 256 + threadIdx.x; e < E; e += stride) {
        const int s = srci[e];
        const int t = tgti[e];
        atomicAdd(&cnt_n[s], 1);          // native int RMW, fire-and-forget
        const float4* __restrict__ pu = (const float4*)(u + (size_t)s * NCH);
        const uint_t* __restrict__ pw = (const uint_t*)(vh + (size_t)t * NCH);
        float us[NCH];
#pragma unroll
        for (int i = 0; i < 8; ++i) {
            float4 a = pu[i];
            us[4*i+0] = a.x; us[4*i+1] = a.y; us[4*i+2] = a.z; us[4*i+3] = a.w;
        }
#pragma unroll
        for (int k = 0; k < 16; ++k) {
            uint_t w2 = pw[k];
            float v0 = __uint_as_float((w2 & 0xFFFFu) << 16);
            float v1 = __uint_as_float(w2 & 0xFFFF0000u);
            const int c0 = 2*k, c1 = 2*k + 1;
            float y0 = us[c0] + v0;
            float y1 = us[c1] + v1;
            sum[c0] += y0; ssq[c0] = fmaf(y0, y0, ssq[c0]);
            sum[c1] += y1; ssq[c1] = fmaf(y1, y1, ssq[c1]);
        }
    }

#pragma unroll
    for (int c = 0; c < NCH; ++c) {
#pragma unroll
        for (int off = 32; off > 0; off >>= 1) {
            sum[c] += __shfl_down(sum[c], off);
            ssq[c] += __shfl_down(ssq[c], off);
        }
    }
    __shared__ float red[4][64];
    const int lane = threadIdx.x & 63, wave = threadIdx.x >> 6;
    if (lane == 0) {
#pragma unroll
        for (int c = 0; c < NCH; ++c) { red[wave][c] = sum[c]; red[wave][NCH+c] = ssq[c]; }
    }
    __syncthreads();
    if (threadIdx.x < 64)
        partials[(size_t)blockIdx.x * 64 + threadIdx.x] =
            red[0][threadIdx.x] + red[1][threadIdx.x]
          + red[2][threadIdx.x] + red[3][threadIdx.x];
}

// --- scan pass 1: per-block (1024 elems) local exclusive scan + block sum --
__global__ __launch_bounds__(256) void k_scan1(
    const int* __restrict__ counts,
    int* __restrict__ offsets,      // block-relative exclusive scan
    int* __restrict__ blksum,       // per-block totals
    int N)
{
    const int tid = threadIdx.x;
    const int base = blockIdx.x * 1024 + tid * 4;
    int c0 = 0, c1 = 0, c2 = 0, c3 = 0;
    if (base + 3 < N) {
        const int4 q = *(const int4*)(counts + base);
        c0 = q.x; c1 = q.y; c2 = q.z; c3 = q.w;
    } else {
        if (base + 0 < N) c0 = counts[base + 0];
        if (base + 1 < N) c1 = counts[base + 1];
        if (base + 2 < N) c2 = counts[base + 2];
        if (base + 3 < N) c3 = counts[base + 3];
    }
    const int tsum = c0 + c1 + c2 + c3;

    const int lane = tid & 63, wv = tid >> 6;
    int val = tsum;
#pragma unroll
    for (int off = 1; off < 64; off <<= 1) {
        int t = __shfl_up(val, off);
        if (lane >= off) val += t;
    }
    __shared__ int wsum[4];
    __shared__ int woff[4];
    __shared__ int btot;
    if (lane == 63) wsum[wv] = val;
    __syncthreads();
    if (tid == 0) {
        int a = 0;
#pragma unroll
        for (int w = 0; w < 4; ++w) { woff[w] = a; a += wsum[w]; }
        btot = a;
        blksum[blockIdx.x] = a;
    }
    __syncthreads();
    (void)btot;
    int run = woff[wv] + (val - tsum);
    if (base + 0 < N) { offsets[base + 0] = run; run += c0; }
    if (base + 1 < N) { offsets[base + 1] = run; run += c1; }
    if (base + 2 < N) { offsets[base + 2] = run; run += c2; }
    if (base + 3 < N) { offsets[base + 3] = run; }
}

// --- scan pass 2: exclusive scan of block sums (<=1024), in place ----------
__global__ __launch_bounds__(1024) void k_scan2(int* __restrict__ blksum, int NBLK)
{
    const int tid = threadIdx.x;
    int v = (tid < NBLK) ? blksum[tid] : 0;
    const int lane = tid & 63, wv = tid >> 6;
    int val = v;
#pragma unroll
    for (int off = 1; off < 64; off <<= 1) {
        int t = __shfl_up(val, off);
        if (lane >= off) val += t;
    }
    __shared__ int wsum[16];
    __shared__ int woff[16];
    if (lane == 63) wsum[wv] = val;
    __syncthreads();
    if (tid == 0) {
        int a = 0;
#pragma unroll
        for (int w = 0; w < 16; ++w) { woff[w] = a; a += wsum[w]; }
    }
    __syncthreads();
    if (tid < NBLK) blksum[tid] = woff[wv] + val - v;   // exclusive
}

// --- scan pass 3: add block base; emit final offsets + cursor --------------
__global__ __launch_bounds__(256) void k_scan3(
    int* __restrict__ offsets, int* __restrict__ cursor,
    const int* __restrict__ blksum, int N)
{
    const int i = blockIdx.x * 256 + threadIdx.x;
    if (i >= N) return;
    const int o = offsets[i] + blksum[i >> 10];
    offsets[i] = o;
    cursor[i]  = o;
}

// --- flat counting-sort scatter: tperm[pos] = tgt, pos per-src cursor ------
__global__ __launch_bounds__(256) void k_tperm(
    const int* __restrict__ srci, const int* __restrict__ tgti,
    int* __restrict__ cur_n, int* __restrict__ tperm, int E)
{
    const int e = blockIdx.x * 256 + threadIdx.x;
    if (e >= E) return;
    const int s = srci[e];
    const int pos = atomicAdd(&cur_n[s], 1);
    tperm[pos] = tgti[e];
}

// --- combine partials -> BN affine a,b -------------------------------------
__global__ __launch_bounds__(256) void k_finalize(
    const float* __restrict__ partials, int nblocks,
    const float* __restrict__ gamma, const float* __restrict__ beta,
    float* __restrict__ ab, float invE)
{
    __shared__ float acc[4][64];
    const int vtx = threadIdx.x & 63, chunk = threadIdx.x >> 6;
    float s = 0.f;
    for (int r = chunk; r < nblocks; r += 4) s += partials[(size_t)r * 64 + vtx];
    acc[chunk][vtx] = s;
    __syncthreads();
    if (threadIdx.x < 64) acc[0][vtx] = acc[0][vtx] + acc[1][vtx] + acc[2][vtx] + acc[3][vtx];
    __syncthreads();
    if (threadIdx.x < 32) {
        const int c = threadIdx.x;
        float mean = acc[0][c] * invE;
        float var  = acc[0][32 + c] * invE - mean * mean;
        float rstd = rsqrtf(var + 1e-5f);
        float a = gamma[c] * rstd;
        ab[c] = a; ab[32 + c] = beta[c] - mean * a;
    }
}

// --- per-node apply: 32-lane group per node, register accumulate -----------
__global__ __launch_bounds__(256) void k_apply_node(
    const float* __restrict__ u, const ushort_t* __restrict__ vh,
    const int* __restrict__ tperm, const int* __restrict__ off_n,
    const int* __restrict__ cnt_n, const float* __restrict__ ab,
    float* __restrict__ out, int N)
{
    const int n = blockIdx.x * 8 + (threadIdx.x >> 5);
    const int c = threadIdx.x & 31;
    if (n >= N) return;

    const int off = off_n[n];
    const int deg = cnt_n[n];
    const float un  = u[(size_t)n * NCH + c];
    const float a_c = ab[c];
    const float b_c = ab[32 + c];

    float acc = 0.f;
    int i = 0;
    for (; i + 4 <= deg; i += 4) {
        int t0 = tperm[off + i + 0];
        int t1 = tperm[off + i + 1];
        int t2 = tperm[off + i + 2];
        int t3 = tperm[off + i + 3];
        ushort_t v0 = vh[(size_t)t0 * NCH + c];
        ushort_t v1 = vh[(size_t)t1 * NCH + c];
        ushort_t v2 = vh[(size_t)t2 * NCH + c];
        ushort_t v3 = vh[(size_t)t3 * NCH + c];
        float z0 = fmaf(a_c, un + bf2f(v0), b_c);
        float z1 = fmaf(a_c, un + bf2f(v1), b_c);
        float z2 = fmaf(a_c, un + bf2f(v2), b_c);
        float z3 = fmaf(a_c, un + bf2f(v3), b_c);
        z0 = (z0 > 0.f) ? z0 : (__expf(z0) - 1.0f);
        z1 = (z1 > 0.f) ? z1 : (__expf(z1) - 1.0f);
        z2 = (z2 > 0.f) ? z2 : (__expf(z2) - 1.0f);
        z3 = (z3 > 0.f) ? z3 : (__expf(z3) - 1.0f);
        acc += (z0 + z1) + (z2 + z3);
    }
    for (; i < deg; ++i) {
        int t = tperm[off + i];
        float z = fmaf(a_c, un + bf2f(vh[(size_t)t * NCH + c]), b_c);
        z = (z > 0.f) ? z : (__expf(z) - 1.0f);
        acc += z;
    }
    out[(size_t)n * NCH + c] = acc;
}

// ===========================================================================
// FALLBACK (round-1 proven path) — only if ws too small
// ===========================================================================
__global__ __launch_bounds__(256) void k_stats_hist(
    const float* __restrict__ x,
    const int* __restrict__ srci, const int* __restrict__ tgti,
    const float* __restrict__ W,
    float* __restrict__ partials, int E)
{
    float sum[NCH], ssq[NCH];
#pragma unroll
    for (int c = 0; c < NCH; ++c) { sum[c] = 0.f; ssq[c] = 0.f; }
    const int stride = gridDim.x * blockDim.x;
    for (int e = blockIdx.x * blockDim.x + threadIdx.x; e < E; e += stride) {
        const int s = srci[e], t = tgti[e];
        const float4* ps = (const float4*)(x + (size_t)s * NCH);
        const float4* pt = (const float4*)(x + (size_t)t * NCH);
        float xs[NCH], dx[NCH];
#pragma unroll
        for (int i = 0; i < 8; ++i) {
            float4 a = ps[i], bb = pt[i];
            xs[4*i+0] = a.x; xs[4*i+1] = a.y; xs[4*i+2] = a.z; xs[4*i+3] = a.w;
            dx[4*i+0] = bb.x - a.x; dx[4*i+1] = bb.y - a.y;
            dx[4*i+2] = bb.z - a.z; dx[4*i+3] = bb.w - a.w;
        }
#pragma unroll
        for (int c = 0; c < NCH; ++c) {
            const float* wr = W + c * 64;
            float y = 0.f;
#pragma unroll
            for (int k = 0; k < NCH; ++k) y = fmaf(wr[k], xs[k], y);
#pragma unroll
            for (int k = 0; k < NCH; ++k) y = fmaf(wr[32 + k], dx[k], y);
            sum[c] += y;
            ssq[c] = fmaf(y, y, ssq[c]);
        }
    }
#pragma unroll
    for (int c = 0; c < NCH; ++c) {
#pragma unroll
        for (int off = 32; off > 0; off >>= 1) {
            sum[c] += __shfl_down(sum[c], off);
            ssq[c] += __shfl_down(ssq[c], off);
        }
    }
    __shared__ float red[4][64];
    const int lane = threadIdx.x & 63, wave = threadIdx.x >> 6;
    if (lane == 0) {
#pragma unroll
        for (int c = 0; c < NCH; ++c) { red[wave][c] = sum[c]; red[wave][NCH+c] = ssq[c]; }
    }
    __syncthreads();
    if (threadIdx.x < 64)
        partials[(size_t)blockIdx.x * 64 + threadIdx.x] =
            red[0][threadIdx.x] + red[1][threadIdx.x] + red[2][threadIdx.x] + red[3][threadIdx.x];
}

__global__ __launch_bounds__(256) void k_apply_atomic(
    const float* __restrict__ x,
    const int* __restrict__ srci, const int* __restrict__ tgti,
    const float* __restrict__ W, const float* __restrict__ ab,
    float* __restrict__ out, int E)
{
    const int e = blockIdx.x * 256 + threadIdx.x;
    if (e >= E) return;
    const int s = srci[e], t = tgti[e];
    const float4* ps = (const float4*)(x + (size_t)s * NCH);
    const float4* pt = (const float4*)(x + (size_t)t * NCH);
    float xs[NCH], dx[NCH];
#pragma unroll
    for (int i = 0; i < 8; ++i) {
        float4 a = ps[i], bb = pt[i];
        xs[4*i+0] = a.x; xs[4*i+1] = a.y; xs[4*i+2] = a.z; xs[4*i+3] = a.w;
        dx[4*i+0] = bb.x - a.x; dx[4*i+1] = bb.y - a.y;
        dx[4*i+2] = bb.z - a.z; dx[4*i+3] = bb.w - a.w;
    }
    float* orow = out + (size_t)s * NCH;
#pragma unroll
    for (int c = 0; c < NCH; ++c) {
        const float* wr = W + c * 64;
        float y = 0.f;
#pragma unroll
        for (int k = 0; k < NCH; ++k) y = fmaf(wr[k], xs[k], y);
#pragma unroll
        for (int k = 0; k < NCH; ++k) y = fmaf(wr[32 + k], dx[k], y);
        float z = fmaf(ab[c], y, ab[32 + c]);
        z = (z > 0.f) ? z : (__expf(z) - 1.0f);
        atomicAdd(orow + c, z);
    }
}

// ===========================================================================
extern "C" void kernel_launch(void* const* d_in, const int* in_sizes, int n_in,
                              void* d_out, int out_size, void* d_ws, size_t ws_size,
                              hipStream_t stream)
{
    const float* x     = (const float*)d_in[0];
    const int*   ei    = (const int*)d_in[1];
    const float* W     = (const float*)d_in[2];
    const float* gamma = (const float*)d_in[3];
    const float* beta  = (const float*)d_in[4];
    const int E = in_sizes[1] / 2;
    const int N = in_sizes[0] / NCH;
    const int* srci = ei;
    const int* tgti = ei + E;

    const int SB = 512;   // stats grid
    const int NBLK = (N + 1023) / 1024;   // scan pass-1 blocks (<=1024)

    // ws: u[N*32]f32 | vh[N*32]bf16 | tperm[E] | cnt_n[N] off_n[N] cur_n[N]
    //     | blksum[1024] | partials[SB*64]f32 | ab[64]f32
    size_t need = (size_t)N * NCH * 4 + (size_t)N * NCH * 2
                + ((size_t)E + 3 * (size_t)N + 1024) * 4
                + ((size_t)SB * 64 + 64) * 4;

    if (NBLK <= 1024 && ws_size >= need) {
        float*    u       = (float*)d_ws;
        ushort_t* vh      = (ushort_t*)(u + (size_t)N * NCH);
        int*      tperm   = (int*)(vh + (size_t)N * NCH);
        int*      cnt_n   = tperm + E;
        int*      off_n   = cnt_n + N;
        int*      cur_n   = off_n + N;
        int*      blksum  = cur_n + N;
        float*    partials= (float*)(blksum + 1024);
        float*    ab      = partials + (size_t)SB * 64;

        hipMemsetAsync(cnt_n, 0, (size_t)N * sizeof(int), stream);
        k_uv<<<(N + 255) / 256, 256, 0, stream>>>(x, W, u, vh, N);
        k_stats_flat<<<SB, 256, 0, stream>>>(u, vh, srci, tgti, cnt_n, partials, E);
        k_scan1<<<NBLK, 256, 0, stream>>>(cnt_n, off_n, blksum, N);
        k_scan2<<<1, 1024, 0, stream>>>(blksum, NBLK);
        k_scan3<<<(N + 255) / 256, 256, 0, stream>>>(off_n, cur_n, blksum, N);
        k_tperm<<<(E + 255) / 256, 256, 0, stream>>>(srci, tgti, cur_n, tperm, E);
        k_finalize<<<1, 256, 0, stream>>>(partials, SB, gamma, beta, ab, 1.0f / (float)E);
        k_apply_node<<<(N + 7) / 8, 256, 0, stream>>>(u, vh, tperm, off_n, cnt_n, ab,
                                                      (float*)d_out, N);
    } else {
        const int SBf = 512;
        float* ab       = (float*)d_ws;
        float* partials = ab + 64;
        hipMemsetAsync(d_out, 0, (size_t)out_size * sizeof(float), stream);
        k_stats_hist<<<SBf, 256, 0, stream>>>(x, srci, tgti, W, partials, E);
        k_finalize<<<1, 256, 0, stream>>>(partials, SBf, gamma, beta, ab, 1.0f / (float)E);
        k_apply_atomic<<<(E + 255) / 256, 256, 0, stream>>>(x, srci, tgti, W, ab,
                                                            (float*)d_out, E);
    }
}

// Round 10
// 360.957 us; speedup vs baseline: 2.3022x; 1.1996x over previous
//
#include <hip/hip_runtime.h>
#include <hip/hip_bf16.h>
#include <math.h>

#define NCH 32

typedef unsigned short ushort_t;
typedef unsigned int uint_t;

static __device__ __forceinline__ float bf2f(ushort_t b) {
    return __uint_as_float(((uint_t)b) << 16);
}
static __device__ __forceinline__ ushort_t f2bf(float f) {
    __hip_bfloat16 h = __float2bfloat16(f);   // round-to-nearest-even
    return *reinterpret_cast<ushort_t*>(&h);
}

// ===========================================================================
// FLAT pipeline (round-10):
//   r9 post-mortem: k_uv was thread-per-node latency-bound (150us, 17% occ);
//   k_tperm write-amplified 16x (105MB for 6.4MB payload, cross-XCD sectors).
//   Fix 1: k_uv -> 32-lane-per-node, LDS W^T, shuffle-broadcast x.
//   Fix 2: k_tperm -> 8 teams (blockIdx&7 ~ XCD), team scans all edges,
//          scatters only its src-partition -> XCD-local L2 write combining.
// ===========================================================================

// --- per-node u (fp32) and vh (bf16): 32 lanes per node --------------------
__global__ __launch_bounds__(256) void k_uv2(
    const float* __restrict__ x, const float* __restrict__ W,
    float* __restrict__ u, ushort_t* __restrict__ vh, int N)
{
    __shared__ float At[NCH * NCH];   // At[k*32+c] = W[c][k] - W[c][32+k]
    __shared__ float Bt[NCH * NCH];   // Bt[k*32+c] = W[c][32+k]
    for (int i = threadIdx.x; i < NCH * NCH; i += 256) {
        const int k = i >> 5, c = i & 31;
        const float w1 = W[c * 64 + k];
        const float w2 = W[c * 64 + 32 + k];
        At[i] = w1 - w2;
        Bt[i] = w2;
    }
    __syncthreads();

    const int n = blockIdx.x * 8 + (threadIdx.x >> 5);
    const int c = threadIdx.x & 31;
    if (n >= N) return;

    const float xc = x[(size_t)n * NCH + c];
    float su = 0.f, sv = 0.f;
#pragma unroll
    for (int k = 0; k < NCH; ++k) {
        const float xk = __shfl(xc, k, 32);
        su = fmaf(At[k * 32 + c], xk, su);
        sv = fmaf(Bt[k * 32 + c], xk, sv);
    }
    u[(size_t)n * NCH + c] = su;
    vh[(size_t)n * NCH + c] = f2bf(sv);
}

// --- flat stats: per-edge y = u[s] + vh[t]; reg sum/ssq; fused histogram ---
__global__ __launch_bounds__(256) void k_stats_flat(
    const float* __restrict__ u, const ushort_t* __restrict__ vh,
    const int* __restrict__ srci, const int* __restrict__ tgti,
    int* __restrict__ cnt_n,
    float* __restrict__ partials, int E)
{
    float sum[NCH], ssq[NCH];
#pragma unroll
    for (int c = 0; c < NCH; ++c) { sum[c] = 0.f; ssq[c] = 0.f; }

    const int stride = gridDim.x * 256;
    for (int e = blockIdx.x * 256 + threadIdx.x; e < E; e += stride) {
        const int s = srci[e];
        const int t = tgti[e];
        atomicAdd(&cnt_n[s], 1);          // native int RMW, fire-and-forget
        const float4* __restrict__ pu = (const float4*)(u + (size_t)s * NCH);
        const uint_t* __restrict__ pw = (const uint_t*)(vh + (size_t)t * NCH);
        float us[NCH];
#pragma unroll
        for (int i = 0; i < 8; ++i) {
            float4 a = pu[i];
            us[4*i+0] = a.x; us[4*i+1] = a.y; us[4*i+2] = a.z; us[4*i+3] = a.w;
        }
#pragma unroll
        for (int k = 0; k < 16; ++k) {
            uint_t w2 = pw[k];
            float v0 = __uint_as_float((w2 & 0xFFFFu) << 16);
            float v1 = __uint_as_float(w2 & 0xFFFF0000u);
            const int c0 = 2*k, c1 = 2*k + 1;
            float y0 = us[c0] + v0;
            float y1 = us[c1] + v1;
            sum[c0] += y0; ssq[c0] = fmaf(y0, y0, ssq[c0]);
            sum[c1] += y1; ssq[c1] = fmaf(y1, y1, ssq[c1]);
        }
    }

#pragma unroll
    for (int c = 0; c < NCH; ++c) {
#pragma unroll
        for (int off = 32; off > 0; off >>= 1) {
            sum[c] += __shfl_down(sum[c], off);
            ssq[c] += __shfl_down(ssq[c], off);
        }
    }
    __shared__ float red[4][64];
    const int lane = threadIdx.x & 63, wave = threadIdx.x >> 6;
    if (lane == 0) {
#pragma unroll
        for (int c = 0; c < NCH; ++c) { red[wave][c] = sum[c]; red[wave][NCH+c] = ssq[c]; }
    }
    __syncthreads();
    if (threadIdx.x < 64)
        partials[(size_t)blockIdx.x * 64 + threadIdx.x] =
            red[0][threadIdx.x] + red[1][threadIdx.x]
          + red[2][threadIdx.x] + red[3][threadIdx.x];
}

// --- scan pass 1: per-block (1024 elems) local exclusive scan + block sum --
__global__ __launch_bounds__(256) void k_scan1(
    const int* __restrict__ counts,
    int* __restrict__ offsets,      // block-relative exclusive scan
    int* __restrict__ blksum,       // per-block totals
    int N)
{
    const int tid = threadIdx.x;
    const int base = blockIdx.x * 1024 + tid * 4;
    int c0 = 0, c1 = 0, c2 = 0, c3 = 0;
    if (base + 3 < N) {
        const int4 q = *(const int4*)(counts + base);
        c0 = q.x; c1 = q.y; c2 = q.z; c3 = q.w;
    } else {
        if (base + 0 < N) c0 = counts[base + 0];
        if (base + 1 < N) c1 = counts[base + 1];
        if (base + 2 < N) c2 = counts[base + 2];
        if (base + 3 < N) c3 = counts[base + 3];
    }
    const int tsum = c0 + c1 + c2 + c3;

    const int lane = tid & 63, wv = tid >> 6;
    int val = tsum;
#pragma unroll
    for (int off = 1; off < 64; off <<= 1) {
        int t = __shfl_up(val, off);
        if (lane >= off) val += t;
    }
    __shared__ int wsum[4];
    __shared__ int woff[4];
    if (lane == 63) wsum[wv] = val;
    __syncthreads();
    if (tid == 0) {
        int a = 0;
#pragma unroll
        for (int w = 0; w < 4; ++w) { woff[w] = a; a += wsum[w]; }
        blksum[blockIdx.x] = a;
    }
    __syncthreads();
    int run = woff[wv] + (val - tsum);
    if (base + 0 < N) { offsets[base + 0] = run; run += c0; }
    if (base + 1 < N) { offsets[base + 1] = run; run += c1; }
    if (base + 2 < N) { offsets[base + 2] = run; run += c2; }
    if (base + 3 < N) { offsets[base + 3] = run; }
}

// --- scan pass 2: exclusive scan of block sums (<=1024), in place ----------
__global__ __launch_bounds__(1024) void k_scan2(int* __restrict__ blksum, int NBLK)
{
    const int tid = threadIdx.x;
    int v = (tid < NBLK) ? blksum[tid] : 0;
    const int lane = tid & 63, wv = tid >> 6;
    int val = v;
#pragma unroll
    for (int off = 1; off < 64; off <<= 1) {
        int t = __shfl_up(val, off);
        if (lane >= off) val += t;
    }
    __shared__ int wsum[16];
    __shared__ int woff[16];
    if (lane == 63) wsum[wv] = val;
    __syncthreads();
    if (tid == 0) {
        int a = 0;
#pragma unroll
        for (int w = 0; w < 16; ++w) { woff[w] = a; a += wsum[w]; }
    }
    __syncthreads();
    if (tid < NBLK) blksum[tid] = woff[wv] + val - v;   // exclusive
}

// --- scan pass 3: add block base; emit final offsets + cursor --------------
__global__ __launch_bounds__(256) void k_scan3(
    int* __restrict__ offsets, int* __restrict__ cursor,
    const int* __restrict__ blksum, int N)
{
    const int i = blockIdx.x * 256 + threadIdx.x;
    if (i >= N) return;
    const int o = offsets[i] + blksum[i >> 10];
    offsets[i] = o;
    cursor[i]  = o;
}

// --- partitioned counting-sort scatter -------------------------------------
// Teams of blocks (blockIdx&7 ~ XCD via round-robin dispatch heuristic).
// Each team scans ALL edges (static stride -> coverage guaranteed even if
// the XCD mapping heuristic is wrong) and scatters only edges whose src
// falls in its partition -> cursor atomics + tperm writes stay XCD-local.
__global__ __launch_bounds__(256) void k_tperm_part(
    const int* __restrict__ srci, const int* __restrict__ tgti,
    int* __restrict__ cur_n, int* __restrict__ tperm,
    int E, uint_t magic)
{
    const int team   = blockIdx.x & 7;
    const int trank  = blockIdx.x >> 3;
    const int tcount = gridDim.x >> 3;
    const int stride = tcount * 256;
    for (int e = trank * 256 + threadIdx.x; e < E; e += stride) {
        const int s = srci[e];
        int part = (int)__umulhi((uint_t)s, magic);   // s / ceil(N/8)
        part = min(part, 7);
        if (part != team) continue;
        const int pos = atomicAdd(&cur_n[s], 1);
        tperm[pos] = tgti[e];
    }
}

// --- combine partials -> BN affine a,b -------------------------------------
__global__ __launch_bounds__(256) void k_finalize(
    const float* __restrict__ partials, int nblocks,
    const float* __restrict__ gamma, const float* __restrict__ beta,
    float* __restrict__ ab, float invE)
{
    __shared__ float acc[4][64];
    const int vtx = threadIdx.x & 63, chunk = threadIdx.x >> 6;
    float s = 0.f;
    for (int r = chunk; r < nblocks; r += 4) s += partials[(size_t)r * 64 + vtx];
    acc[chunk][vtx] = s;
    __syncthreads();
    if (threadIdx.x < 64) acc[0][vtx] = acc[0][vtx] + acc[1][vtx] + acc[2][vtx] + acc[3][vtx];
    __syncthreads();
    if (threadIdx.x < 32) {
        const int c = threadIdx.x;
        float mean = acc[0][c] * invE;
        float var  = acc[0][32 + c] * invE - mean * mean;
        float rstd = rsqrtf(var + 1e-5f);
        float a = gamma[c] * rstd;
        ab[c] = a; ab[32 + c] = beta[c] - mean * a;
    }
}

// --- per-node apply: 32-lane group per node, register accumulate -----------
__global__ __launch_bounds__(256) void k_apply_node(
    const float* __restrict__ u, const ushort_t* __restrict__ vh,
    const int* __restrict__ tperm, const int* __restrict__ off_n,
    const int* __restrict__ cnt_n, const float* __restrict__ ab,
    float* __restrict__ out, int N)
{
    const int n = blockIdx.x * 8 + (threadIdx.x >> 5);
    const int c = threadIdx.x & 31;
    if (n >= N) return;

    const int off = off_n[n];
    const int deg = cnt_n[n];
    const float un  = u[(size_t)n * NCH + c];
    const float a_c = ab[c];
    const float b_c = ab[32 + c];

    float acc = 0.f;
    int i = 0;
    for (; i + 4 <= deg; i += 4) {
        int t0 = tperm[off + i + 0];
        int t1 = tperm[off + i + 1];
        int t2 = tperm[off + i + 2];
        int t3 = tperm[off + i + 3];
        ushort_t v0 = vh[(size_t)t0 * NCH + c];
        ushort_t v1 = vh[(size_t)t1 * NCH + c];
        ushort_t v2 = vh[(size_t)t2 * NCH + c];
        ushort_t v3 = vh[(size_t)t3 * NCH + c];
        float z0 = fmaf(a_c, un + bf2f(v0), b_c);
        float z1 = fmaf(a_c, un + bf2f(v1), b_c);
        float z2 = fmaf(a_c, un + bf2f(v2), b_c);
        float z3 = fmaf(a_c, un + bf2f(v3), b_c);
        z0 = (z0 > 0.f) ? z0 : (__expf(z0) - 1.0f);
        z1 = (z1 > 0.f) ? z1 : (__expf(z1) - 1.0f);
        z2 = (z2 > 0.f) ? z2 : (__expf(z2) - 1.0f);
        z3 = (z3 > 0.f) ? z3 : (__expf(z3) - 1.0f);
        acc += (z0 + z1) + (z2 + z3);
    }
    for (; i < deg; ++i) {
        int t = tperm[off + i];
        float z = fmaf(a_c, un + bf2f(vh[(size_t)t * NCH + c]), b_c);
        z = (z > 0.f) ? z : (__expf(z) - 1.0f);
        acc += z;
    }
    out[(size_t)n * NCH + c] = acc;
}

// ===========================================================================
// FALLBACK (round-1 proven path) — only if ws too small
// ===========================================================================
__global__ __launch_bounds__(256) void k_stats_hist(
    const float* __restrict__ x,
    const int* __restrict__ srci, const int* __restrict__ tgti,
    const float* __restrict__ W,
    float* __restrict__ partials, int E)
{
    float sum[NCH], ssq[NCH];
#pragma unroll
    for (int c = 0; c < NCH; ++c) { sum[c] = 0.f; ssq[c] = 0.f; }
    const int stride = gridDim.x * blockDim.x;
    for (int e = blockIdx.x * blockDim.x + threadIdx.x; e < E; e += stride) {
        const int s = srci[e], t = tgti[e];
        const float4* ps = (const float4*)(x + (size_t)s * NCH);
        const float4* pt = (const float4*)(x + (size_t)t * NCH);
        float xs[NCH], dx[NCH];
#pragma unroll
        for (int i = 0; i < 8; ++i) {
            float4 a = ps[i], bb = pt[i];
            xs[4*i+0] = a.x; xs[4*i+1] = a.y; xs[4*i+2] = a.z; xs[4*i+3] = a.w;
            dx[4*i+0] = bb.x - a.x; dx[4*i+1] = bb.y - a.y;
            dx[4*i+2] = bb.z - a.z; dx[4*i+3] = bb.w - a.w;
        }
#pragma unroll
        for (int c = 0; c < NCH; ++c) {
            const float* wr = W + c * 64;
            float y = 0.f;
#pragma unroll
            for (int k = 0; k < NCH; ++k) y = fmaf(wr[k], xs[k], y);
#pragma unroll
            for (int k = 0; k < NCH; ++k) y = fmaf(wr[32 + k], dx[k], y);
            sum[c] += y;
            ssq[c] = fmaf(y, y, ssq[c]);
        }
    }
#pragma unroll
    for (int c = 0; c < NCH; ++c) {
#pragma unroll
        for (int off = 32; off > 0; off >>= 1) {
            sum[c] += __shfl_down(sum[c], off);
            ssq[c] += __shfl_down(ssq[c], off);
        }
    }
    __shared__ float red[4][64];
    const int lane = threadIdx.x & 63, wave = threadIdx.x >> 6;
    if (lane == 0) {
#pragma unroll
        for (int c = 0; c < NCH; ++c) { red[wave][c] = sum[c]; red[wave][NCH+c] = ssq[c]; }
    }
    __syncthreads();
    if (threadIdx.x < 64)
        partials[(size_t)blockIdx.x * 64 + threadIdx.x] =
            red[0][threadIdx.x] + red[1][threadIdx.x] + red[2][threadIdx.x] + red[3][threadIdx.x];
}

__global__ __launch_bounds__(256) void k_apply_atomic(
    const float* __restrict__ x,
    const int* __restrict__ srci, const int* __restrict__ tgti,
    const float* __restrict__ W, const float* __restrict__ ab,
    float* __restrict__ out, int E)
{
    const int e = blockIdx.x * 256 + threadIdx.x;
    if (e >= E) return;
    const int s = srci[e], t = tgti[e];
    const float4* ps = (const float4*)(x + (size_t)s * NCH);
    const float4* pt = (const float4*)(x + (size_t)t * NCH);
    float xs[NCH], dx[NCH];
#pragma unroll
    for (int i = 0; i < 8; ++i) {
        float4 a = ps[i], bb = pt[i];
        xs[4*i+0] = a.x; xs[4*i+1] = a.y; xs[4*i+2] = a.z; xs[4*i+3] = a.w;
        dx[4*i+0] = bb.x - a.x; dx[4*i+1] = bb.y - a.y;
        dx[4*i+2] = bb.z - a.z; dx[4*i+3] = bb.w - a.w;
    }
    float* orow = out + (size_t)s * NCH;
#pragma unroll
    for (int c = 0; c < NCH; ++c) {
        const float* wr = W + c * 64;
        float y = 0.f;
#pragma unroll
        for (int k = 0; k < NCH; ++k) y = fmaf(wr[k], xs[k], y);
#pragma unroll
        for (int k = 0; k < NCH; ++k) y = fmaf(wr[32 + k], dx[k], y);
        float z = fmaf(ab[c], y, ab[32 + c]);
        z = (z > 0.f) ? z : (__expf(z) - 1.0f);
        atomicAdd(orow + c, z);
    }
}

// ===========================================================================
extern "C" void kernel_launch(void* const* d_in, const int* in_sizes, int n_in,
                              void* d_out, int out_size, void* d_ws, size_t ws_size,
                              hipStream_t stream)
{
    const float* x     = (const float*)d_in[0];
    const int*   ei    = (const int*)d_in[1];
    const float* W     = (const float*)d_in[2];
    const float* gamma = (const float*)d_in[3];
    const float* beta  = (const float*)d_in[4];
    const int E = in_sizes[1] / 2;
    const int N = in_sizes[0] / NCH;
    const int* srci = ei;
    const int* tgti = ei + E;

    const int SB = 512;   // stats grid
    const int NBLK = (N + 1023) / 1024;   // scan pass-1 blocks (<=1024)

    // partition magic: part = umulhi(s, magic) == s / ceil(N/8)
    const uint_t partDiv = (uint_t)((N + 7) / 8);
    const uint_t magic = (uint_t)((0x100000000ULL + partDiv - 1) / partDiv);

    // ws: u[N*32]f32 | vh[N*32]bf16 | tperm[E] | cnt_n[N] off_n[N] cur_n[N]
    //     | blksum[1024] | partials[SB*64]f32 | ab[64]f32
    size_t need = (size_t)N * NCH * 4 + (size_t)N * NCH * 2
                + ((size_t)E + 3 * (size_t)N + 1024) * 4
                + ((size_t)SB * 64 + 64) * 4;

    if (NBLK <= 1024 && ws_size >= need) {
        float*    u       = (float*)d_ws;
        ushort_t* vh      = (ushort_t*)(u + (size_t)N * NCH);
        int*      tperm   = (int*)(vh + (size_t)N * NCH);
        int*      cnt_n   = tperm + E;
        int*      off_n   = cnt_n + N;
        int*      cur_n   = off_n + N;
        int*      blksum  = cur_n + N;
        float*    partials= (float*)(blksum + 1024);
        float*    ab      = partials + (size_t)SB * 64;

        hipMemsetAsync(cnt_n, 0, (size_t)N * sizeof(int), stream);
        k_uv2<<<(N + 7) / 8, 256, 0, stream>>>(x, W, u, vh, N);
        k_stats_flat<<<SB, 256, 0, stream>>>(u, vh, srci, tgti, cnt_n, partials, E);
        k_scan1<<<NBLK, 256, 0, stream>>>(cnt_n, off_n, blksum, N);
        k_scan2<<<1, 1024, 0, stream>>>(blksum, NBLK);
        k_scan3<<<(N + 255) / 256, 256, 0, stream>>>(off_n, cur_n, blksum, N);
        k_tperm_part<<<512, 256, 0, stream>>>(srci, tgti, cur_n, tperm, E, magic);
        k_finalize<<<1, 256, 0, stream>>>(partials, SB, gamma, beta, ab, 1.0f / (float)E);
        k_apply_node<<<(N + 7) / 8, 256, 0, stream>>>(u, vh, tperm, off_n, cnt_n, ab,
                                                      (float*)d_out, N);
    } else {
        const int SBf = 512;
        float* ab       = (float*)d_ws;
        float* partials = ab + 64;
        hipMemsetAsync(d_out, 0, (size_t)out_size * sizeof(float), stream);
        k_stats_hist<<<SBf, 256, 0, stream>>>(x, srci, tgti, W, partials, E);
        k_finalize<<<1, 256, 0, stream>>>(partials, SBf, gamma, beta, ab, 1.0f / (float)E);
        k_apply_atomic<<<(E + 255) / 256, 256, 0, stream>>>(x, srci, tgti, W, ab,
                                                            (float*)d_out, E);
    }
}